// Round 10
// baseline (338.363 us; speedup 1.0000x reference)
//
#include <hip/hip_runtime.h>
#include <hip/hip_bf16.h>
#include <stdint.h>

#define Bn 4
#define Sn 2048
#define Dn 1024
#define Hn 16
#define HDn 64
#define Mn (Bn * Sn)  // 8192
#define PS 44         // P_lds row stride (elems): padded vs 32 to spread banks

typedef __attribute__((ext_vector_type(8))) __bf16 bf16x8;
typedef __attribute__((ext_vector_type(4))) __bf16 bf16x4;
typedef __attribute__((ext_vector_type(4))) float f32x4;

#if __has_builtin(__builtin_amdgcn_exp2f)
#define EXP2F(x) __builtin_amdgcn_exp2f(x)
#else
#define EXP2F(x) exp2f(x)
#endif

typedef __attribute__((address_space(1))) unsigned int as1_uint;
typedef __attribute__((address_space(3))) unsigned int as3_uint;

__device__ __forceinline__ void gld_lds16(const void* g, void* l) {
  __builtin_amdgcn_global_load_lds((const as1_uint*)g, (as3_uint*)l, 16, 0, 0);
}

// ------------- fused f32 -> bf16 conversion for all 7 arrays --------------
struct CvtArgs {
  const float* src[7];
};
__constant__ const size_t kGb[8] = {0,       1048576, 2097152, 3145728,
                                    3276800, 3407872, 3538944, 3670016};

__global__ __launch_bounds__(256) void cvt_all(CvtArgs a, __bf16* __restrict__ dst) {
  size_t i = (size_t)blockIdx.x * 256 + threadIdx.x;
  if (i >= 3670016) return;
  int s = 0;
#pragma unroll
  for (int k = 1; k < 7; k++) s += (i >= kGb[k]) ? 1 : 0;
  const float4* sp = (const float4*)a.src[s] + 2 * (i - kGb[s]);
  float4 x = sp[0], y = sp[1];
  bf16x8 o;
  o[0] = (__bf16)x.x; o[1] = (__bf16)x.y; o[2] = (__bf16)x.z; o[3] = (__bf16)x.w;
  o[4] = (__bf16)y.x; o[5] = (__bf16)y.y; o[6] = (__bf16)y.z; o[7] = (__bf16)y.w;
  *(bf16x8*)(dst + 8 * i) = o;
}

// ------------- 128x128 tile GEMM, C = A @ W^T (+bias)*scale --------------
// MODE 0: bf16 row-major out. MODE 1: f32 row-major out.
// MODE 2: bf16 transposed-per-head out Vt[b][h][c][s] (for attention V).
template <int MODE>
__device__ __forceinline__ void gemm128_body(const __bf16* __restrict__ A,
                                             const __bf16* __restrict__ Bw,
                                             const float* __restrict__ bias,
                                             void* __restrict__ Cout, int m0, int n0,
                                             float scale) {
  __shared__ __align__(16) __bf16 lA[128 * 32];
  __shared__ __align__(16) __bf16 lB[128 * 32];
  const int tid = threadIdx.x;
  const int wave = tid >> 6, lane = tid & 63, quad = lane >> 4, l15 = lane & 15;
  const int wm = wave >> 1, wn = wave & 1;
  f32x4 acc[4][4] = {};
  const char* Ab = (const char*)(A + (size_t)m0 * Dn);
  const char* Bb = (const char*)(Bw + (size_t)n0 * Dn);
  char* lAc = (char*)lA;
  char* lBc = (char*)lB;
  const int o0 = tid * 16, o1 = o0 + 4096;
  const int r0 = o0 >> 6, c0 = o0 & 63;
  const int r1 = o1 >> 6, c1 = o1 & 63;

  for (int k0 = 0; k0 < Dn; k0 += 32) {
    __syncthreads();
    gld_lds16(Ab + (size_t)r0 * 2048 + k0 * 2 + c0, lAc + o0);
    gld_lds16(Ab + (size_t)r1 * 2048 + k0 * 2 + c1, lAc + o1);
    gld_lds16(Bb + (size_t)r0 * 2048 + k0 * 2 + c0, lBc + o0);
    gld_lds16(Bb + (size_t)r1 * 2048 + k0 * 2 + c1, lBc + o1);
    __syncthreads();
    bf16x8 af[4], bfv[4];
#pragma unroll
    for (int i = 0; i < 4; i++)
      af[i] = *(const bf16x8*)(lA + (wm * 64 + i * 16 + l15) * 32 + quad * 8);
#pragma unroll
    for (int t = 0; t < 4; t++)
      bfv[t] = *(const bf16x8*)(lB + (wn * 64 + t * 16 + l15) * 32 + quad * 8);
#pragma unroll
    for (int i = 0; i < 4; i++)
#pragma unroll
      for (int t = 0; t < 4; t++)
        acc[i][t] = __builtin_amdgcn_mfma_f32_16x16x32_bf16(af[i], bfv[t], acc[i][t], 0, 0, 0);
  }
  // epilogue: C/D layout col=lane&15, row=quad*4+reg (m89-verified)
#pragma unroll
  for (int i = 0; i < 4; i++) {
    const int rowb = m0 + wm * 64 + i * 16 + quad * 4;
#pragma unroll
    for (int t = 0; t < 4; t++) {
      const int col = n0 + wn * 64 + t * 16 + l15;
      const float bb = bias[col];
      if (MODE == 2) {
        // Vt[b][h][c][s]: 4 consecutive s per lane -> one 8B store
        const int b = rowb >> 11, s = rowb & 2047;
        const int h = col >> 6, c = col & 63;
        bf16x4 pk;
#pragma unroll
        for (int r = 0; r < 4; r++) pk[r] = (__bf16)(acc[i][t][r] + bb);
        *(bf16x4*)((__bf16*)Cout + (((size_t)(b * Hn + h) * HDn + c) * Sn + s)) = pk;
      } else {
#pragma unroll
        for (int r = 0; r < 4; r++) {
          float v = (acc[i][t][r] + bb) * scale;
          if (MODE == 1)
            ((float*)Cout)[(size_t)(rowb + r) * Dn + col] = v;
          else
            ((__bf16*)Cout)[(size_t)(rowb + r) * Dn + col] = (__bf16)v;
        }
      }
    }
  }
}

// R7: XCD-aware chunked swizzle on the GEMM grids (kept; R7 measured win).
__global__ __launch_bounds__(256, 3) void qkv_gemm(
    const __bf16* __restrict__ X, const __bf16* __restrict__ W,
    const float* __restrict__ bq, const float* __restrict__ bk,
    const float* __restrict__ bv, __bf16* __restrict__ out) {
  const int lin = blockIdx.x + (blockIdx.y << 3) + (blockIdx.z << 9);
  const int wg = (lin & 7) * 192 + (lin >> 3);
  const int z = wg >> 9, rem = wg & 511;
  const int m0 = (rem >> 3) * 128, n0 = (rem & 7) * 128;
  if (z == 0) {
    // fold softmax scale (1/8)*log2(e) into Q so scores are in exp2 domain
    gemm128_body<0>(X, W, bq, out, m0, n0, 0.18033688011112042f);
  } else if (z == 1) {
    gemm128_body<0>(X + (size_t)Mn * Dn, W + (size_t)Dn * Dn, bk,
                    out + (size_t)Mn * Dn, m0, n0, 1.0f);
  } else {
    gemm128_body<2>(X + 2 * (size_t)Mn * Dn, W + 2 * (size_t)Dn * Dn, bv,
                    out + 2 * (size_t)Mn * Dn, m0, n0, 1.0f);
  }
}

__global__ __launch_bounds__(256, 3) void out_gemm(const __bf16* __restrict__ A,
                                                   const __bf16* __restrict__ W,
                                                   const float* __restrict__ bo,
                                                   float* __restrict__ out) {
  const int lin = blockIdx.x + (blockIdx.y << 3);
  const int wg = (lin & 7) * 64 + (lin >> 3);
  const int m0 = (wg >> 3) * 128, n0 = (wg & 7) * 128;
  gemm128_body<1>(A, W, bo, out, m0, n0, 1.0f);
}

// ---------------- flash attention, one wave = 32 q-rows -------------------
// R11 = R9 structure (LDS-staged K/V, best 87.8us) with 32 q-rows/wave to
// quadruple independent blocks per CU.
// R10 post-mortem: key-split's 77.8KB block didn't co-schedule 2/CU ->
// occupancy flat, merge overhead only (90.5us). Reverted.
// R9 arithmetic: issue density only ~25% (52k cyc of issue in 210k) -- the
// per-block barrier locksteps 4 waves into the same phase; with 2 blocks/CU
// there are just 2 independent phase streams. Fix: 4 waves x 32 q (q-tile
// 128/block, 1024 blocks). LDS = plds 11264 + kbuf 8192 + vbuf 8192 =
// 27648B -> 5 blocks/CU by LDS, grid-capped 4/CU = 16 waves = 4/SIMD.
// Unlike R6 (q=32 died on per-lane strided loads), staging is cooperative:
// per-wave work halves proportionally, and 4 phase-offset blocks fill the
// serial-chain gaps. No key-split -> no merge epilogue. Staging roles,
// swizzled LDS, setprio, XCD swizzle: byte-identical to R9.
__global__ __launch_bounds__(256, 2) void flash_attn(const __bf16* __restrict__ Q,
                                                     const __bf16* __restrict__ K,
                                                     const __bf16* __restrict__ Vt,
                                                     __bf16* __restrict__ Aout) {
  __shared__ __align__(16) __bf16 plds[4][32 * PS];  // 11264 B
  __shared__ __align__(16) __bf16 kbuf[2][32 * 64];  // 2 x 4KB: [row=key][128B]
  __shared__ __align__(16) __bf16 vbuf[2][32 * 64];  // 2 x 4KB: [row][c=row|row+32]
  const int tid = threadIdx.x;
  const int wave = tid >> 6, lane = tid & 63, quad = lane >> 4, l15 = lane & 15;
  // XCD swizzle: 1024 blocks, XCD (lin&7) owns wg [(lin&7)*128, +128) = 8
  // consecutive bh -> 4MB K/V working set resident in its private L2.
  const int lin = blockIdx.x + (blockIdx.y << 4);  // gridDim.x == 16
  const int wg = (lin & 7) * 128 + (lin >> 3);
  const int bh = wg >> 4, qt = wg & 15;
  const int b = bh >> 4, h = bh & 15;
  const int q0 = qt * 128 + wave * 32;
  const __bf16* Qb = Q + ((size_t)b * Sn) * Dn + h * HDn;
  const char* Kbase = (const char*)(K + ((size_t)b * Sn) * Dn + h * HDn);
  const char* Vbase = (const char*)(Vt + (size_t)(b * Hn + h) * HDn * Sn);
  __bf16* myP = &plds[wave][0];

  // staging roles: thread tid stages 16B of K and 16B of V per kstep.
  // K: LDS row=tid>>3, stored block=tid&7 holds logical block j^(row&7)
  //    -> source col j = (tid&7)^(row&7) (within the 128B row).
  // V tile row r: [c=r s0..31 | c=r+32 s0..31]; logical block j: half=j>>2,
  //    squad=j&3 -> source (c=r+32*half, s=squad*8).
  const int srow = tid >> 3;                // 0..31
  const int kjsrc = (tid & 7) ^ (srow & 7);
  const int vjsrc = (tid & 7) ^ (srow & 7);
  const int vhalf = vjsrc >> 2, vsq = vjsrc & 3;
  const size_t ksrc_row = (size_t)srow * (Dn * 2) + kjsrc * 16;
  const size_t vsrc_row = (size_t)(srow + 32 * vhalf) * (Sn * 2) + vsq * 16;

#define STAGE(BUFI, KEY0)                                                         \
  {                                                                               \
    gld_lds16(Kbase + (size_t)(KEY0) * (Dn * 2) + ksrc_row,                       \
              (char*)&kbuf[BUFI][0] + tid * 16);                                  \
    gld_lds16(Vbase + (size_t)(KEY0) * 2 + vsrc_row,                              \
              (char*)&vbuf[BUFI][0] + tid * 16);                                  \
  }

  // resident Q fragments, used as MFMA *B*-operand: B[k=d][n=q]
  bf16x8 qf[2][2];
#pragma unroll
  for (int iq = 0; iq < 2; iq++)
#pragma unroll
    for (int s = 0; s < 2; s++)
      qf[iq][s] = *(const bf16x8*)(Qb + (size_t)(q0 + iq * 16 + l15) * Dn + s * 32 + quad * 8);

  f32x4 O[4][2] = {};  // O^T accumulators: [mc][iq], col=q=l15, row=c=quad*4+r
  float li[2] = {};    // per-lane row-sum partials, lane l15 owns q=iq*16+l15

  STAGE(0, 0)
  __syncthreads();

#pragma unroll 2
  for (int kt = 0; kt < Sn / 32; kt++) {
    const int cur = kt & 1, nxt = cur ^ 1;
    // stage kt+1 tiles (async; lands before the end-of-kstep barrier)
    if (kt < Sn / 32 - 1) STAGE(nxt, (kt + 1) * 32)
    // fragments from LDS (swizzled reads; 2-way conflicts = free)
    bf16x8 kf[2][2], vf[4];
#pragma unroll
    for (int tk = 0; tk < 2; tk++)
#pragma unroll
      for (int s = 0; s < 2; s++) {
        const int jp = (s * 4 + quad) ^ (l15 & 7);
        kf[tk][s] = *(const bf16x8*)((const char*)&kbuf[cur][0] +
                                     (tk * 16 + l15) * 128 + jp * 16);
      }
#pragma unroll
    for (int mc = 0; mc < 4; mc++) {
      const int jp = ((mc >> 1) * 4 + quad) ^ (l15 & 7);
      vf[mc] = *(const bf16x8*)((const char*)&vbuf[cur][0] +
                                ((mc & 1) * 16 + l15) * 128 + jp * 16);
    }
    // S^T = K · Q^T : D[m=key][n=q]
    f32x4 sa[2][2];
    __builtin_amdgcn_s_setprio(1);
#pragma unroll
    for (int tk = 0; tk < 2; tk++)
#pragma unroll
      for (int iq = 0; iq < 2; iq++) {
        f32x4 z = {0.f, 0.f, 0.f, 0.f};
        z = __builtin_amdgcn_mfma_f32_16x16x32_bf16(kf[tk][0], qf[iq][0], z, 0, 0, 0);
        z = __builtin_amdgcn_mfma_f32_16x16x32_bf16(kf[tk][1], qf[iq][1], z, 0, 0, 0);
        sa[tk][iq] = z;
      }
    __builtin_amdgcn_s_setprio(0);
    // P = exp2(S^T): lane has 4 consecutive keys at q=iq*16+l15 -> b64 store
#pragma unroll
    for (int tk = 0; tk < 2; tk++)
#pragma unroll
      for (int iq = 0; iq < 2; iq++) {
        bf16x4 pk;
#pragma unroll
        for (int r = 0; r < 4; r++) {
          float p = EXP2F(sa[tk][iq][r]);
          li[iq] += p;
          pk[r] = (__bf16)p;
        }
        *(bf16x4*)(myP + (iq * 16 + l15) * PS + tk * 16 + quad * 4) = pk;
      }
    // PV: O^T[c][q] += Vt-frag (A) x P-frag (B). B[k=key][n=q]: lane l15=q,
    // keys quad*8..+7 contiguous in P[q][key] -> two b64 reads.
    // Same-wave DS ops execute in order: no barrier needed (R1/R2-verified).
    __builtin_amdgcn_s_setprio(1);
#pragma unroll
    for (int iq = 0; iq < 2; iq++) {
      bf16x4 plo = *(const bf16x4*)(myP + (iq * 16 + l15) * PS + quad * 8);
      bf16x4 phi = *(const bf16x4*)(myP + (iq * 16 + l15) * PS + quad * 8 + 4);
      bf16x8 pf = __builtin_shufflevector(plo, phi, 0, 1, 2, 3, 4, 5, 6, 7);
#pragma unroll
      for (int mc = 0; mc < 4; mc++)
        O[mc][iq] = __builtin_amdgcn_mfma_f32_16x16x32_bf16(vf[mc], pf, O[mc][iq], 0, 0, 0);
    }
    __builtin_amdgcn_s_setprio(0);
    // barrier: staging(nxt) landed + all waves done reading cur
    __syncthreads();
  }
#undef STAGE
  // normalize: full row-sum = reduce partials across quads (keys split by quad)
  float inv[2];
#pragma unroll
  for (int iq = 0; iq < 2; iq++) {
    float s = li[iq];
    s += __shfl_xor(s, 16);
    s += __shfl_xor(s, 32);
    inv[iq] = 1.0f / s;
  }
  // store O^T tiles: lane has 4 consecutive c at fixed q -> 8B packed stores
#pragma unroll
  for (int mc = 0; mc < 4; mc++)
#pragma unroll
    for (int iq = 0; iq < 2; iq++) {
      bf16x4 o;
#pragma unroll
      for (int r = 0; r < 4; r++) o[r] = (__bf16)(O[mc][iq][r] * inv[iq]);
      *(bf16x4*)(Aout + ((size_t)b * Sn + q0 + iq * 16 + l15) * Dn + h * HDn + mc * 16 +
                 quad * 4) = o;
    }
}

extern "C" void kernel_launch(void* const* d_in, const int* in_sizes, int n_in,
                              void* d_out, int out_size, void* d_ws, size_t ws_size,
                              hipStream_t stream) {
  const float* bq = (const float*)d_in[4];
  const float* bk = (const float*)d_in[6];
  const float* bv = (const float*)d_in[8];
  const float* bo = (const float*)d_in[10];

  const size_t MD = (size_t)Mn * Dn;  // 8,388,608
  const size_t DD = (size_t)Dn * Dn;  // 1,048,576
  // ws layout (bf16): X[3*MD] | W[4*DD] | QKV(Q,K,Vt)[3*MD] | Attn[MD]
  __bf16* Xbf  = (__bf16*)d_ws;
  __bf16* Wbf  = Xbf + 3 * MD;
  __bf16* QKV  = Wbf + 4 * DD;
  __bf16* Attn = QKV + 3 * MD;

  CvtArgs ca;
  ca.src[0] = (const float*)d_in[0];  // query
  ca.src[1] = (const float*)d_in[1];  // key
  ca.src[2] = (const float*)d_in[2];  // value
  ca.src[3] = (const float*)d_in[3];  // Wq
  ca.src[4] = (const float*)d_in[5];  // Wk
  ca.src[5] = (const float*)d_in[7];  // Wv
  ca.src[6] = (const float*)d_in[9];  // Wo
  cvt_all<<<14336, 256, 0, stream>>>(ca, Xbf);

  qkv_gemm<<<dim3(Dn / 128, Mn / 128, 3), 256, 0, stream>>>(Xbf, Wbf, bq, bk, bv, QKV);
  flash_attn<<<dim3(Sn / 128, Bn * Hn), 256, 0, stream>>>(QKV, QKV + MD, QKV + 2 * MD, Attn);
  out_gemm<<<dim3(Dn / 128, Mn / 128), 256, 0, stream>>>(Attn, Wbf + 3 * DD, bo, (float*)d_out);
}

// Round 11
// 336.962 us; speedup vs baseline: 1.0042x; 1.0042x over previous
//
#include <hip/hip_runtime.h>
#include <hip/hip_bf16.h>
#include <stdint.h>

#define Bn 4
#define Sn 2048
#define Dn 1024
#define Hn 16
#define HDn 64
#define Mn (Bn * Sn)  // 8192

typedef __attribute__((ext_vector_type(8))) __bf16 bf16x8;
typedef __attribute__((ext_vector_type(4))) __bf16 bf16x4;
typedef __attribute__((ext_vector_type(4))) float f32x4;
typedef __attribute__((ext_vector_type(16))) float f32x16;

#if __has_builtin(__builtin_amdgcn_exp2f)
#define EXP2F(x) __builtin_amdgcn_exp2f(x)
#else
#define EXP2F(x) exp2f(x)
#endif

typedef __attribute__((address_space(1))) unsigned int as1_uint;
typedef __attribute__((address_space(3))) unsigned int as3_uint;

__device__ __forceinline__ void gld_lds16(const void* g, void* l) {
  __builtin_amdgcn_global_load_lds((const as1_uint*)g, (as3_uint*)l, 16, 0, 0);
}

// pack two f32 -> one u32 of 2 bf16 (T12 recipe; R8-validated)
__device__ __forceinline__ unsigned pk_bf16(float lo, float hi) {
  unsigned r;
  asm("v_cvt_pk_bf16_f32 %0, %1, %2" : "=v"(r) : "v"(lo), "v"(hi));
  return r;
}
// v_permlane32_swap_b32 a, b : lane i<32: a'=a, b'=a[i+32]
//                              lane i>=32: a'=b[i-32], b'=b
#define PLSWAP(a_, b_) asm("v_permlane32_swap_b32 %0, %1" : "+v"(a_), "+v"(b_))

// ------------- fused f32 -> bf16 conversion for all 7 arrays --------------
struct CvtArgs {
  const float* src[7];
};
__constant__ const size_t kGb[8] = {0,       1048576, 2097152, 3145728,
                                    3276800, 3407872, 3538944, 3670016};

__global__ __launch_bounds__(256) void cvt_all(CvtArgs a, __bf16* __restrict__ dst) {
  size_t i = (size_t)blockIdx.x * 256 + threadIdx.x;
  if (i >= 3670016) return;
  int s = 0;
#pragma unroll
  for (int k = 1; k < 7; k++) s += (i >= kGb[k]) ? 1 : 0;
  const float4* sp = (const float4*)a.src[s] + 2 * (i - kGb[s]);
  float4 x = sp[0], y = sp[1];
  bf16x8 o;
  o[0] = (__bf16)x.x; o[1] = (__bf16)x.y; o[2] = (__bf16)x.z; o[3] = (__bf16)x.w;
  o[4] = (__bf16)y.x; o[5] = (__bf16)y.y; o[6] = (__bf16)y.z; o[7] = (__bf16)y.w;
  *(bf16x8*)(dst + 8 * i) = o;
}

// ------------- 128x128 tile GEMM, C = A @ W^T (+bias)*scale --------------
// MODE 0: bf16 row-major out. MODE 1: f32 row-major out.
// MODE 2: bf16 transposed-per-head out Vt[b][h][c][s] (for attention V).
template <int MODE>
__device__ __forceinline__ void gemm128_body(const __bf16* __restrict__ A,
                                             const __bf16* __restrict__ Bw,
                                             const float* __restrict__ bias,
                                             void* __restrict__ Cout, int m0, int n0,
                                             float scale) {
  __shared__ __align__(16) __bf16 lA[128 * 32];
  __shared__ __align__(16) __bf16 lB[128 * 32];
  const int tid = threadIdx.x;
  const int wave = tid >> 6, lane = tid & 63, quad = lane >> 4, l15 = lane & 15;
  const int wm = wave >> 1, wn = wave & 1;
  f32x4 acc[4][4] = {};
  const char* Ab = (const char*)(A + (size_t)m0 * Dn);
  const char* Bb = (const char*)(Bw + (size_t)n0 * Dn);
  char* lAc = (char*)lA;
  char* lBc = (char*)lB;
  const int o0 = tid * 16, o1 = o0 + 4096;
  const int r0 = o0 >> 6, c0 = o0 & 63;
  const int r1 = o1 >> 6, c1 = o1 & 63;

  for (int k0 = 0; k0 < Dn; k0 += 32) {
    __syncthreads();
    gld_lds16(Ab + (size_t)r0 * 2048 + k0 * 2 + c0, lAc + o0);
    gld_lds16(Ab + (size_t)r1 * 2048 + k0 * 2 + c1, lAc + o1);
    gld_lds16(Bb + (size_t)r0 * 2048 + k0 * 2 + c0, lBc + o0);
    gld_lds16(Bb + (size_t)r1 * 2048 + k0 * 2 + c1, lBc + o1);
    __syncthreads();
    bf16x8 af[4], bfv[4];
#pragma unroll
    for (int i = 0; i < 4; i++)
      af[i] = *(const bf16x8*)(lA + (wm * 64 + i * 16 + l15) * 32 + quad * 8);
#pragma unroll
    for (int t = 0; t < 4; t++)
      bfv[t] = *(const bf16x8*)(lB + (wn * 64 + t * 16 + l15) * 32 + quad * 8);
#pragma unroll
    for (int i = 0; i < 4; i++)
#pragma unroll
      for (int t = 0; t < 4; t++)
        acc[i][t] = __builtin_amdgcn_mfma_f32_16x16x32_bf16(af[i], bfv[t], acc[i][t], 0, 0, 0);
  }
  // epilogue: C/D layout col=lane&15, row=quad*4+reg (m89-verified)
#pragma unroll
  for (int i = 0; i < 4; i++) {
    const int rowb = m0 + wm * 64 + i * 16 + quad * 4;
#pragma unroll
    for (int t = 0; t < 4; t++) {
      const int col = n0 + wn * 64 + t * 16 + l15;
      const float bb = bias[col];
      if (MODE == 2) {
        // Vt[b][h][c][s]: 4 consecutive s per lane -> one 8B store
        const int b = rowb >> 11, s = rowb & 2047;
        const int h = col >> 6, c = col & 63;
        bf16x4 pk;
#pragma unroll
        for (int r = 0; r < 4; r++) pk[r] = (__bf16)(acc[i][t][r] + bb);
        *(bf16x4*)((__bf16*)Cout + (((size_t)(b * Hn + h) * HDn + c) * Sn + s)) = pk;
      } else {
#pragma unroll
        for (int r = 0; r < 4; r++) {
          float v = (acc[i][t][r] + bb) * scale;
          if (MODE == 1)
            ((float*)Cout)[(size_t)(rowb + r) * Dn + col] = v;
          else
            ((__bf16*)Cout)[(size_t)(rowb + r) * Dn + col] = (__bf16)v;
        }
      }
    }
  }
}

// R7: XCD-aware chunked swizzle on the GEMM grids (kept; R7 measured win).
__global__ __launch_bounds__(256, 3) void qkv_gemm(
    const __bf16* __restrict__ X, const __bf16* __restrict__ W,
    const float* __restrict__ bq, const float* __restrict__ bk,
    const float* __restrict__ bv, __bf16* __restrict__ out) {
  const int lin = blockIdx.x + (blockIdx.y << 3) + (blockIdx.z << 9);
  const int wg = (lin & 7) * 192 + (lin >> 3);
  const int z = wg >> 9, rem = wg & 511;
  const int m0 = (rem >> 3) * 128, n0 = (rem & 7) * 128;
  if (z == 0) {
    // fold softmax scale (1/8)*log2(e) into Q so scores are in exp2 domain
    gemm128_body<0>(X, W, bq, out, m0, n0, 0.18033688011112042f);
  } else if (z == 1) {
    gemm128_body<0>(X + (size_t)Mn * Dn, W + (size_t)Dn * Dn, bk,
                    out + (size_t)Mn * Dn, m0, n0, 1.0f);
  } else {
    gemm128_body<2>(X + 2 * (size_t)Mn * Dn, W + 2 * (size_t)Dn * Dn, bv,
                    out + 2 * (size_t)Mn * Dn, m0, n0, 1.0f);
  }
}

__global__ __launch_bounds__(256, 3) void out_gemm(const __bf16* __restrict__ A,
                                                   const __bf16* __restrict__ W,
                                                   const float* __restrict__ bo,
                                                   float* __restrict__ out) {
  const int lin = blockIdx.x + (blockIdx.y << 3);
  const int wg = (lin & 7) * 64 + (lin >> 3);
  const int m0 = (wg >> 3) * 128, n0 = (wg & 7) * 128;
  gemm128_body<1>(A, W, bo, out, m0, n0, 1.0f);
}

// ---------------- flash attention, one wave = 32 q-rows -------------------
// R12 = R11's cooperative LDS staging + R8's in-register softmax.
// Pipe accounting at R11 (84.4us): DS ~73% busy (kf/vf 96 + P-rt 48 cyc per
// wave-kstep at m134 rates) > VALU 40% > MFMA 36%. The P LDS round-trip is
// 1/3 of DS AND sits serially in the chain. R8 already validated (passed,
// same absmax) the 32x32-MFMA + cvt_pk + permlane32_swap in-register P;
// its slowness was the per-lane strided global K/V loads, which R9/R11's
// block-cooperative staging fixed. Merge both:
//  - STAGE identical to R11 (same tiles, same XOR swizzle, same roles)
//  - S^T = K.Q^T: 4 chained mfma_32x32x16 (C: col=q=lane&31,
//    row=key=(reg&3)+8*(reg>>2)+4*(lane>>5), m74-verified)
//  - kf/vf LDS reads in 32x32 A-frag shape: row=l31, logical slot
//    (t*2+hi) / (ct*4+kh*2+hi), physical = logical ^ (l31&7)
//  - P: 16 exp2 -> 8 cvt_pk -> 4 permlane32_swap -> PV B-frags (R8 math)
//  - PV: 4 mfma_32x32x16. No P LDS traffic; DS -33%; MFMA insts halved.
// LDS 16KB/block; grid 1024 = 4 blocks/CU = 4 waves/SIMD (VGPR ~60-90).
// XCD swizzle kept: each XCD owns 8 consecutive bh (K/V L2-resident).
__global__ __launch_bounds__(256, 2) void flash_attn(const __bf16* __restrict__ Q,
                                                     const __bf16* __restrict__ K,
                                                     const __bf16* __restrict__ Vt,
                                                     __bf16* __restrict__ Aout) {
  __shared__ __align__(16) __bf16 kbuf[2][32 * 64];  // 2 x 4KB: [row=key][8 slots]
  __shared__ __align__(16) __bf16 vbuf[2][32 * 64];  // 2 x 4KB: [row][c=row|row+32]
  const int tid = threadIdx.x;
  const int wave = tid >> 6, lane = tid & 63;
  const int l31 = lane & 31, hi = lane >> 5;
  // XCD swizzle: 1024 blocks, XCD (lin&7) owns wg [(lin&7)*128, +128) = 8
  // consecutive bh -> 4MB K/V working set resident in its private L2.
  const int lin = blockIdx.x + (blockIdx.y << 4);  // gridDim.x == 16
  const int wg = (lin & 7) * 128 + (lin >> 3);
  const int bh = wg >> 4, qt = wg & 15;
  const int b = bh >> 4, h = bh & 15;
  const int q0 = qt * 128 + wave * 32;
  const __bf16* Qb = Q + ((size_t)b * Sn + q0 + l31) * Dn + h * HDn + hi * 8;
  const char* Kbase = (const char*)(K + ((size_t)b * Sn) * Dn + h * HDn);
  const char* Vbase = (const char*)(Vt + (size_t)(b * Hn + h) * HDn * Sn);

  // staging roles (identical to R11): thread tid stages 16B of K and V.
  // K: LDS row=tid>>3, stored slot tid&7 holds logical slot (tid&7)^(row&7).
  // V row r: [c=r s0..31 | c=r+32 s0..31]; logical j: vhalf=j>>2, vsq=j&3.
  const int srow = tid >> 3;  // 0..31
  const int jsrc = (tid & 7) ^ (srow & 7);
  const int vhalf = jsrc >> 2, vsq = jsrc & 3;
  const size_t ksrc_row = (size_t)srow * (Dn * 2) + jsrc * 16;
  const size_t vsrc_row = (size_t)(srow + 32 * vhalf) * (Sn * 2) + vsq * 16;

#define STAGE(BUFI, KEY0)                                                         \
  {                                                                               \
    gld_lds16(Kbase + (size_t)(KEY0) * (Dn * 2) + ksrc_row,                       \
              (char*)&kbuf[BUFI][0] + tid * 16);                                  \
    gld_lds16(Vbase + (size_t)(KEY0) * 2 + vsrc_row,                              \
              (char*)&vbuf[BUFI][0] + tid * 16);                                  \
  }

  // resident Q fragments: B[k=d][n=q], lane n=l31, k=hi*8+j (+16t)
  bf16x8 qf[4];
#pragma unroll
  for (int t = 0; t < 4; t++) qf[t] = *(const bf16x8*)(Qb + 16 * t);

  f32x16 O0 = {}, O1 = {};  // O^T acc: c-tile 0/1, col=q=l31
  float li0 = 0.f, li1 = 0.f, li2 = 0.f, li3 = 0.f;

  STAGE(0, 0)
  __syncthreads();

#pragma unroll 2
  for (int kt = 0; kt < Sn / 32; kt++) {
    const int cur = kt & 1, nxt = cur ^ 1;
    // stage kt+1 tiles (async; lands before the end-of-kstep barrier)
    if (kt < Sn / 32 - 1) STAGE(nxt, (kt + 1) * 32)
    // K fragments: A[m=key=l31][k=d hi*8+j+16t]; swizzled slot reads
    bf16x8 kf[4], vfr[2][2];
#pragma unroll
    for (int t = 0; t < 4; t++) {
      const int jp = (t * 2 + hi) ^ (l31 & 7);
      kf[t] = *(const bf16x8*)((const char*)&kbuf[cur][0] + l31 * 128 + jp * 16);
    }
    // V fragments: A[m=c=ct*32+l31][k=key hi*8+j+16kh]
#pragma unroll
    for (int ct = 0; ct < 2; ct++)
#pragma unroll
      for (int kh = 0; kh < 2; kh++) {
        const int jp = (ct * 4 + kh * 2 + hi) ^ (l31 & 7);
        vfr[ct][kh] = *(const bf16x8*)((const char*)&vbuf[cur][0] + l31 * 128 + jp * 16);
      }
    // S^T(32 keys x 32 q) over d=64: 4 chained 32x32x16 MFMAs
    f32x16 s = {};
    __builtin_amdgcn_s_setprio(1);
#pragma unroll
    for (int t = 0; t < 4; t++)
      s = __builtin_amdgcn_mfma_f32_32x32x16_bf16(kf[t], qf[t], s, 0, 0, 0);
    __builtin_amdgcn_s_setprio(0);
    // P = exp2(S^T) (max-free; Q pre-scaled by (1/8)*log2e), row-sums
    float p[16];
#pragma unroll
    for (int r = 0; r < 16; r++) p[r] = EXP2F(s[r]);
    li0 += p[0] + p[4] + p[8] + p[12];
    li1 += p[1] + p[5] + p[9] + p[13];
    li2 += p[2] + p[6] + p[10] + p[14];
    li3 += p[3] + p[7] + p[11] + p[15];
    // pack to bf16 pairs and cross-half redistribute (R8-validated):
    // dest B-frag key j at lane needs keys hi*8+j (+16 for 2nd mfma)
    unsigned A1 = pk_bf16(p[0], p[1]), B1 = pk_bf16(p[2], p[3]);
    unsigned A2 = pk_bf16(p[4], p[5]), B2 = pk_bf16(p[6], p[7]);
    unsigned C1 = pk_bf16(p[8], p[9]), D1 = pk_bf16(p[10], p[11]);
    unsigned C2 = pk_bf16(p[12], p[13]), D2 = pk_bf16(p[14], p[15]);
    PLSWAP(A1, A2);
    PLSWAP(B1, B2);
    PLSWAP(C1, C2);
    PLSWAP(D1, D2);
    uint4 wA = {A1, B1, A2, B2};  // keys 0-15 frag (both halves)
    uint4 wB = {C1, D1, C2, D2};  // keys 16-31 frag
    bf16x8 pbA = __builtin_bit_cast(bf16x8, wA);
    bf16x8 pbB = __builtin_bit_cast(bf16x8, wB);
    // PV: O^T[c][q] += Vt-frag x P-frag
    __builtin_amdgcn_s_setprio(1);
    O0 = __builtin_amdgcn_mfma_f32_32x32x16_bf16(vfr[0][0], pbA, O0, 0, 0, 0);
    O0 = __builtin_amdgcn_mfma_f32_32x32x16_bf16(vfr[0][1], pbB, O0, 0, 0, 0);
    O1 = __builtin_amdgcn_mfma_f32_32x32x16_bf16(vfr[1][0], pbA, O1, 0, 0, 0);
    O1 = __builtin_amdgcn_mfma_f32_32x32x16_bf16(vfr[1][1], pbB, O1, 0, 0, 0);
    __builtin_amdgcn_s_setprio(0);
    // barrier: staging(nxt) landed + all waves done reading cur
    __syncthreads();
  }
#undef STAGE

  // row-sum: lane (q,hi) holds 16 of 32 key-rows; partner lane^32 the rest
  float li = (li0 + li1) + (li2 + li3);
  li += __shfl_xor(li, 32);
  const float inv = 1.0f / li;
  // store O^T: c = 8g + 4*hi + j (+32 for O1), row q0+l31 -> 8B stores
  __bf16* Ab = Aout + ((size_t)b * Sn + q0 + l31) * Dn + h * HDn + hi * 4;
#pragma unroll
  for (int g = 0; g < 4; g++) {
    bf16x4 o0, o1;
#pragma unroll
    for (int j = 0; j < 4; j++) {
      o0[j] = (__bf16)(O0[4 * g + j] * inv);
      o1[j] = (__bf16)(O1[4 * g + j] * inv);
    }
    *(bf16x4*)(Ab + g * 8) = o0;
    *(bf16x4*)(Ab + 32 + g * 8) = o1;
  }
}

extern "C" void kernel_launch(void* const* d_in, const int* in_sizes, int n_in,
                              void* d_out, int out_size, void* d_ws, size_t ws_size,
                              hipStream_t stream) {
  const float* bq = (const float*)d_in[4];
  const float* bk = (const float*)d_in[6];
  const float* bv = (const float*)d_in[8];
  const float* bo = (const float*)d_in[10];

  const size_t MD = (size_t)Mn * Dn;  // 8,388,608
  const size_t DD = (size_t)Dn * Dn;  // 1,048,576
  // ws layout (bf16): X[3*MD] | W[4*DD] | QKV(Q,K,Vt)[3*MD] | Attn[MD]
  __bf16* Xbf  = (__bf16*)d_ws;
  __bf16* Wbf  = Xbf + 3 * MD;
  __bf16* QKV  = Wbf + 4 * DD;
  __bf16* Attn = QKV + 3 * MD;

  CvtArgs ca;
  ca.src[0] = (const float*)d_in[0];  // query
  ca.src[1] = (const float*)d_in[1];  // key
  ca.src[2] = (const float*)d_in[2];  // value
  ca.src[3] = (const float*)d_in[3];  // Wq
  ca.src[4] = (const float*)d_in[5];  // Wk
  ca.src[5] = (const float*)d_in[7];  // Wv
  ca.src[6] = (const float*)d_in[9];  // Wo
  cvt_all<<<14336, 256, 0, stream>>>(ca, Xbf);

  qkv_gemm<<<dim3(Dn / 128, Mn / 128, 3), 256, 0, stream>>>(Xbf, Wbf, bq, bk, bv, QKV);
  flash_attn<<<dim3(Sn / 128, Bn * Hn), 256, 0, stream>>>(QKV, QKV + MD, QKV + 2 * MD, Attn);
  out_gemm<<<dim3(Dn / 128, Mn / 128), 256, 0, stream>>>(Attn, Wbf + 3 * DD, bo, (float*)d_out);
}

// Round 14
// 329.367 us; speedup vs baseline: 1.0273x; 1.0231x over previous
//
#include <hip/hip_runtime.h>
#include <hip/hip_bf16.h>
#include <stdint.h>

#define Bn 4
#define Sn 2048
#define Dn 1024
#define Hn 16
#define HDn 64
#define Mn (Bn * Sn)  // 8192

typedef __attribute__((ext_vector_type(8))) __bf16 bf16x8;
typedef __attribute__((ext_vector_type(4))) __bf16 bf16x4;
typedef __attribute__((ext_vector_type(4))) float f32x4;
typedef __attribute__((ext_vector_type(16))) float f32x16;

#if __has_builtin(__builtin_amdgcn_exp2f)
#define EXP2F(x) __builtin_amdgcn_exp2f(x)
#else
#define EXP2F(x) exp2f(x)
#endif

typedef __attribute__((address_space(1))) unsigned int as1_uint;
typedef __attribute__((address_space(3))) unsigned int as3_uint;

__device__ __forceinline__ void gld_lds16(const void* g, void* l) {
  __builtin_amdgcn_global_load_lds((const as1_uint*)g, (as3_uint*)l, 16, 0, 0);
}

// pack two f32 -> one u32 of 2 bf16 (T12 recipe; R8-validated)
__device__ __forceinline__ unsigned pk_bf16(float lo, float hi) {
  unsigned r;
  asm("v_cvt_pk_bf16_f32 %0, %1, %2" : "=v"(r) : "v"(lo), "v"(hi));
  return r;
}
// v_permlane32_swap_b32 a, b : lane i<32: a'=a, b'=a[i+32]
//                              lane i>=32: a'=b[i-32], b'=b
#define PLSWAP(a_, b_) asm("v_permlane32_swap_b32 %0, %1" : "+v"(a_), "+v"(b_))

// ------------- fused f32 -> bf16 conversion for all 7 arrays --------------
struct CvtArgs {
  const float* src[7];
};
__constant__ const size_t kGb[8] = {0,       1048576, 2097152, 3145728,
                                    3276800, 3407872, 3538944, 3670016};

__global__ __launch_bounds__(256) void cvt_all(CvtArgs a, __bf16* __restrict__ dst) {
  size_t i = (size_t)blockIdx.x * 256 + threadIdx.x;
  if (i >= 3670016) return;
  int s = 0;
#pragma unroll
  for (int k = 1; k < 7; k++) s += (i >= kGb[k]) ? 1 : 0;
  const float4* sp = (const float4*)a.src[s] + 2 * (i - kGb[s]);
  float4 x = sp[0], y = sp[1];
  bf16x8 o;
  o[0] = (__bf16)x.x; o[1] = (__bf16)x.y; o[2] = (__bf16)x.z; o[3] = (__bf16)x.w;
  o[4] = (__bf16)y.x; o[5] = (__bf16)y.y; o[6] = (__bf16)y.z; o[7] = (__bf16)y.w;
  *(bf16x8*)(dst + 8 * i) = o;
}

// ------------- 128x128 tile GEMM, C = A @ W^T (+bias)*scale --------------
// MODE 0: bf16 row-major out. MODE 1: f32 row-major out.
// MODE 2: bf16 transposed-per-head out Vt[b][h][c][s] (for attention V).
template <int MODE>
__device__ __forceinline__ void gemm128_body(const __bf16* __restrict__ A,
                                             const __bf16* __restrict__ Bw,
                                             const float* __restrict__ bias,
                                             void* __restrict__ Cout, int m0, int n0,
                                             float scale) {
  __shared__ __align__(16) __bf16 lA[128 * 32];
  __shared__ __align__(16) __bf16 lB[128 * 32];
  const int tid = threadIdx.x;
  const int wave = tid >> 6, lane = tid & 63, quad = lane >> 4, l15 = lane & 15;
  const int wm = wave >> 1, wn = wave & 1;
  f32x4 acc[4][4] = {};
  const char* Ab = (const char*)(A + (size_t)m0 * Dn);
  const char* Bb = (const char*)(Bw + (size_t)n0 * Dn);
  char* lAc = (char*)lA;
  char* lBc = (char*)lB;
  const int o0 = tid * 16, o1 = o0 + 4096;
  const int r0 = o0 >> 6, c0 = o0 & 63;
  const int r1 = o1 >> 6, c1 = o1 & 63;

  for (int k0 = 0; k0 < Dn; k0 += 32) {
    __syncthreads();
    gld_lds16(Ab + (size_t)r0 * 2048 + k0 * 2 + c0, lAc + o0);
    gld_lds16(Ab + (size_t)r1 * 2048 + k0 * 2 + c1, lAc + o1);
    gld_lds16(Bb + (size_t)r0 * 2048 + k0 * 2 + c0, lBc + o0);
    gld_lds16(Bb + (size_t)r1 * 2048 + k0 * 2 + c1, lBc + o1);
    __syncthreads();
    bf16x8 af[4], bfv[4];
#pragma unroll
    for (int i = 0; i < 4; i++)
      af[i] = *(const bf16x8*)(lA + (wm * 64 + i * 16 + l15) * 32 + quad * 8);
#pragma unroll
    for (int t = 0; t < 4; t++)
      bfv[t] = *(const bf16x8*)(lB + (wn * 64 + t * 16 + l15) * 32 + quad * 8);
#pragma unroll
    for (int i = 0; i < 4; i++)
#pragma unroll
      for (int t = 0; t < 4; t++)
        acc[i][t] = __builtin_amdgcn_mfma_f32_16x16x32_bf16(af[i], bfv[t], acc[i][t], 0, 0, 0);
  }
  // epilogue: C/D layout col=lane&15, row=quad*4+reg (m89-verified)
#pragma unroll
  for (int i = 0; i < 4; i++) {
    const int rowb = m0 + wm * 64 + i * 16 + quad * 4;
#pragma unroll
    for (int t = 0; t < 4; t++) {
      const int col = n0 + wn * 64 + t * 16 + l15;
      const float bb = bias[col];
      if (MODE == 2) {
        // Vt[b][h][c][s]: 4 consecutive s per lane -> one 8B store
        const int b = rowb >> 11, s = rowb & 2047;
        const int h = col >> 6, c = col & 63;
        bf16x4 pk;
#pragma unroll
        for (int r = 0; r < 4; r++) pk[r] = (__bf16)(acc[i][t][r] + bb);
        *(bf16x4*)((__bf16*)Cout + (((size_t)(b * Hn + h) * HDn + c) * Sn + s)) = pk;
      } else {
#pragma unroll
        for (int r = 0; r < 4; r++) {
          float v = (acc[i][t][r] + bb) * scale;
          if (MODE == 1)
            ((float*)Cout)[(size_t)(rowb + r) * Dn + col] = v;
          else
            ((__bf16*)Cout)[(size_t)(rowb + r) * Dn + col] = (__bf16)v;
        }
      }
    }
  }
}

// R7: XCD-aware chunked swizzle on the GEMM grids (kept; R7 measured win).
__global__ __launch_bounds__(256, 3) void qkv_gemm(
    const __bf16* __restrict__ X, const __bf16* __restrict__ W,
    const float* __restrict__ bq, const float* __restrict__ bk,
    const float* __restrict__ bv, __bf16* __restrict__ out) {
  const int lin = blockIdx.x + (blockIdx.y << 3) + (blockIdx.z << 9);
  const int wg = (lin & 7) * 192 + (lin >> 3);
  const int z = wg >> 9, rem = wg & 511;
  const int m0 = (rem >> 3) * 128, n0 = (rem & 7) * 128;
  if (z == 0) {
    // fold softmax scale (1/8)*log2(e) into Q so scores are in exp2 domain
    gemm128_body<0>(X, W, bq, out, m0, n0, 0.18033688011112042f);
  } else if (z == 1) {
    gemm128_body<0>(X + (size_t)Mn * Dn, W + (size_t)Dn * Dn, bk,
                    out + (size_t)Mn * Dn, m0, n0, 1.0f);
  } else {
    gemm128_body<2>(X + 2 * (size_t)Mn * Dn, W + 2 * (size_t)Dn * Dn, bv,
                    out + 2 * (size_t)Mn * Dn, m0, n0, 1.0f);
  }
}

__global__ __launch_bounds__(256, 3) void out_gemm(const __bf16* __restrict__ A,
                                                   const __bf16* __restrict__ W,
                                                   const float* __restrict__ bo,
                                                   float* __restrict__ out) {
  const int lin = blockIdx.x + (blockIdx.y << 3);
  const int wg = (lin & 7) * 64 + (lin >> 3);
  const int m0 = (wg >> 3) * 128, n0 = (wg & 7) * 128;
  gemm128_body<1>(A, W, bo, out, m0, n0, 1.0f);
}

// ---------------- flash attention, one wave = 32 q-rows -------------------
// R13 = R12 (in-register softmax, 84.5us) + full-rank LDS swizzle.
// R12 post-mortem: P-roundtrip removal saved ~49k DS cyc/CU but introduced
// SQ_LDS_BANK_CONFLICT = 2^23 (+4 cyc per ds_read_b128 ~= 33k cyc/CU) ->
// exact wash. Cause: fragment reads use row=l31 with slot jp = s ^ (l31&7);
// lanes sharing l31&7 but differing in l31>>3 get the SAME jp, and the
// 128B row stride is bank-neutral -> 4-way conflicts. Fix: fold the row's
// high bits into the swizzle: g(row) = (row&7) ^ ((row>>3)<<1). Any 8 lanes
// with equal l31&7 now hit jp offsets {0,2,4,6}(+hi) -> all distinct; any
// 8 consecutive lanes still distinct; 16-lane halves at worst 2-way (free,
// m136). Storage side: jsrc = (tid&7) ^ g(srow); staging stays linear-dest
// + permuted-source (rule #21). Everything else identical to R12.
__global__ __launch_bounds__(256, 2) void flash_attn(const __bf16* __restrict__ Q,
                                                     const __bf16* __restrict__ K,
                                                     const __bf16* __restrict__ Vt,
                                                     __bf16* __restrict__ Aout) {
  __shared__ __align__(16) __bf16 kbuf[2][32 * 64];  // 2 x 4KB: [row=key][8 slots]
  __shared__ __align__(16) __bf16 vbuf[2][32 * 64];  // 2 x 4KB: [row][c=row|row+32]
  const int tid = threadIdx.x;
  const int wave = tid >> 6, lane = tid & 63;
  const int l31 = lane & 31, hi = lane >> 5;
  const int grow = (l31 & 7) ^ ((l31 >> 3) << 1);  // read-side row swizzle
  // XCD swizzle: 1024 blocks, XCD (lin&7) owns wg [(lin&7)*128, +128) = 8
  // consecutive bh -> 4MB K/V working set resident in its private L2.
  const int lin = blockIdx.x + (blockIdx.y << 4);  // gridDim.x == 16
  const int wg = (lin & 7) * 128 + (lin >> 3);
  const int bh = wg >> 4, qt = wg & 15;
  const int b = bh >> 4, h = bh & 15;
  const int q0 = qt * 128 + wave * 32;
  const __bf16* Qb = Q + ((size_t)b * Sn + q0 + l31) * Dn + h * HDn + hi * 8;
  const char* Kbase = (const char*)(K + ((size_t)b * Sn) * Dn + h * HDn);
  const char* Vbase = (const char*)(Vt + (size_t)(b * Hn + h) * HDn * Sn);

  // staging roles: thread tid stages 16B of K and V. LDS row = tid>>3,
  // physical slot tid&7 holds logical slot (tid&7) ^ g(row),
  // g(row) = (row&7) ^ ((row>>3)<<1).
  // V row r: [c=r s0..31 | c=r+32 s0..31]; logical j: vhalf=j>>2, vsq=j&3.
  const int srow = tid >> 3;  // 0..31
  const int jsrc = (tid & 7) ^ (srow & 7) ^ ((srow >> 3) << 1);
  const int vhalf = jsrc >> 2, vsq = jsrc & 3;
  const size_t ksrc_row = (size_t)srow * (Dn * 2) + jsrc * 16;
  const size_t vsrc_row = (size_t)(srow + 32 * vhalf) * (Sn * 2) + vsq * 16;

#define STAGE(BUFI, KEY0)                                                         \
  {                                                                               \
    gld_lds16(Kbase + (size_t)(KEY0) * (Dn * 2) + ksrc_row,                       \
              (char*)&kbuf[BUFI][0] + tid * 16);                                  \
    gld_lds16(Vbase + (size_t)(KEY0) * 2 + vsrc_row,                              \
              (char*)&vbuf[BUFI][0] + tid * 16);                                  \
  }

  // resident Q fragments: B[k=d][n=q], lane n=l31, k=hi*8+j (+16t)
  bf16x8 qf[4];
#pragma unroll
  for (int t = 0; t < 4; t++) qf[t] = *(const bf16x8*)(Qb + 16 * t);

  f32x16 O0 = {}, O1 = {};  // O^T acc: c-tile 0/1, col=q=l31
  float li0 = 0.f, li1 = 0.f, li2 = 0.f, li3 = 0.f;

  STAGE(0, 0)
  __syncthreads();

#pragma unroll 2
  for (int kt = 0; kt < Sn / 32; kt++) {
    const int cur = kt & 1, nxt = cur ^ 1;
    // stage kt+1 tiles (async; lands before the end-of-kstep barrier)
    if (kt < Sn / 32 - 1) STAGE(nxt, (kt + 1) * 32)
    // K fragments: A[m=key=l31][k=d hi*8+j+16t]; swizzled slot reads
    bf16x8 kf[4], vfr[2][2];
#pragma unroll
    for (int t = 0; t < 4; t++) {
      const int jp = (t * 2 + hi) ^ grow;
      kf[t] = *(const bf16x8*)((const char*)&kbuf[cur][0] + l31 * 128 + jp * 16);
    }
    // V fragments: A[m=c=ct*32+l31][k=key hi*8+j+16kh]
#pragma unroll
    for (int ct = 0; ct < 2; ct++)
#pragma unroll
      for (int kh = 0; kh < 2; kh++) {
        const int jp = (ct * 4 + kh * 2 + hi) ^ grow;
        vfr[ct][kh] = *(const bf16x8*)((const char*)&vbuf[cur][0] + l31 * 128 + jp * 16);
      }
    // S^T(32 keys x 32 q) over d=64: 4 chained 32x32x16 MFMAs
    f32x16 s = {};
    __builtin_amdgcn_s_setprio(1);
#pragma unroll
    for (int t = 0; t < 4; t++)
      s = __builtin_amdgcn_mfma_f32_32x32x16_bf16(kf[t], qf[t], s, 0, 0, 0);
    __builtin_amdgcn_s_setprio(0);
    // P = exp2(S^T) (max-free; Q pre-scaled by (1/8)*log2e), row-sums
    float p[16];
#pragma unroll
    for (int r = 0; r < 16; r++) p[r] = EXP2F(s[r]);
    li0 += p[0] + p[4] + p[8] + p[12];
    li1 += p[1] + p[5] + p[9] + p[13];
    li2 += p[2] + p[6] + p[10] + p[14];
    li3 += p[3] + p[7] + p[11] + p[15];
    // pack to bf16 pairs and cross-half redistribute (R8-validated):
    // dest B-frag key j at lane needs keys hi*8+j (+16 for 2nd mfma)
    unsigned A1 = pk_bf16(p[0], p[1]), B1 = pk_bf16(p[2], p[3]);
    unsigned A2 = pk_bf16(p[4], p[5]), B2 = pk_bf16(p[6], p[7]);
    unsigned C1 = pk_bf16(p[8], p[9]), D1 = pk_bf16(p[10], p[11]);
    unsigned C2 = pk_bf16(p[12], p[13]), D2 = pk_bf16(p[14], p[15]);
    PLSWAP(A1, A2);
    PLSWAP(B1, B2);
    PLSWAP(C1, C2);
    PLSWAP(D1, D2);
    uint4 wA = {A1, B1, A2, B2};  // keys 0-15 frag (both halves)
    uint4 wB = {C1, D1, C2, D2};  // keys 16-31 frag
    bf16x8 pbA = __builtin_bit_cast(bf16x8, wA);
    bf16x8 pbB = __builtin_bit_cast(bf16x8, wB);
    // PV: O^T[c][q] += Vt-frag x P-frag
    __builtin_amdgcn_s_setprio(1);
    O0 = __builtin_amdgcn_mfma_f32_32x32x16_bf16(vfr[0][0], pbA, O0, 0, 0, 0);
    O0 = __builtin_amdgcn_mfma_f32_32x32x16_bf16(vfr[0][1], pbB, O0, 0, 0, 0);
    O1 = __builtin_amdgcn_mfma_f32_32x32x16_bf16(vfr[1][0], pbA, O1, 0, 0, 0);
    O1 = __builtin_amdgcn_mfma_f32_32x32x16_bf16(vfr[1][1], pbB, O1, 0, 0, 0);
    __builtin_amdgcn_s_setprio(0);
    // barrier: staging(nxt) landed + all waves done reading cur
    __syncthreads();
  }
#undef STAGE

  // row-sum: lane (q,hi) holds 16 of 32 key-rows; partner lane^32 the rest
  float li = (li0 + li1) + (li2 + li3);
  li += __shfl_xor(li, 32);
  const float inv = 1.0f / li;
  // store O^T: c = 8g + 4*hi + j (+32 for O1), row q0+l31 -> 8B stores
  __bf16* Ab = Aout + ((size_t)b * Sn + q0 + l31) * Dn + h * HDn + hi * 4;
#pragma unroll
  for (int g = 0; g < 4; g++) {
    bf16x4 o0, o1;
#pragma unroll
    for (int j = 0; j < 4; j++) {
      o0[j] = (__bf16)(O0[4 * g + j] * inv);
      o1[j] = (__bf16)(O1[4 * g + j] * inv);
    }
    *(bf16x4*)(Ab + g * 8) = o0;
    *(bf16x4*)(Ab + 32 + g * 8) = o1;
  }
}

extern "C" void kernel_launch(void* const* d_in, const int* in_sizes, int n_in,
                              void* d_out, int out_size, void* d_ws, size_t ws_size,
                              hipStream_t stream) {
  const float* bq = (const float*)d_in[4];
  const float* bk = (const float*)d_in[6];
  const float* bv = (const float*)d_in[8];
  const float* bo = (const float*)d_in[10];

  const size_t MD = (size_t)Mn * Dn;  // 8,388,608
  const size_t DD = (size_t)Dn * Dn;  // 1,048,576
  // ws layout (bf16): X[3*MD] | W[4*DD] | QKV(Q,K,Vt)[3*MD] | Attn[MD]
  __bf16* Xbf  = (__bf16*)d_ws;
  __bf16* Wbf  = Xbf + 3 * MD;
  __bf16* QKV  = Wbf + 4 * DD;
  __bf16* Attn = QKV + 3 * MD;

  CvtArgs ca;
  ca.src[0] = (const float*)d_in[0];  // query
  ca.src[1] = (const float*)d_in[1];  // key
  ca.src[2] = (const float*)d_in[2];  // value
  ca.src[3] = (const float*)d_in[3];  // Wq
  ca.src[4] = (const float*)d_in[5];  // Wk
  ca.src[5] = (const float*)d_in[7];  // Wv
  ca.src[6] = (const float*)d_in[9];  // Wo
  cvt_all<<<14336, 256, 0, stream>>>(ca, Xbf);

  qkv_gemm<<<dim3(Dn / 128, Mn / 128, 3), 256, 0, stream>>>(Xbf, Wbf, bq, bk, bv, QKV);
  flash_attn<<<dim3(Sn / 128, Bn * Hn), 256, 0, stream>>>(QKV, QKV + MD, QKV + 2 * MD, Attn);
  out_gemm<<<dim3(Dn / 128, Mn / 128), 256, 0, stream>>>(Attn, Wbf + 3 * DD, bo, (float*)d_out);
}